// Round 1
// baseline (1480.434 us; speedup 1.0000x reference)
//
#include <hip/hip_runtime.h>
#include <hip/hip_bf16.h>

typedef __bf16 bf16_t;
typedef __bf16 bf16x8 __attribute__((ext_vector_type(8)));
typedef float  f32x4  __attribute__((ext_vector_type(4)));

static __device__ __forceinline__ void gload_lds16(const void* g, void* l) {
  __builtin_amdgcn_global_load_lds((const __attribute__((address_space(1))) void*)g,
                                   (__attribute__((address_space(3))) void*)l, 16, 0, 0);
}

// ------------------------------------------------------------------
// GEMM  C = A * B^T (+bias, optional relu), A: MxK bf16, B: NxK bf16
// 128x128 tile, BK=32, 4 waves (2x2), 4x4 16x16x32 frags per wave.
// ------------------------------------------------------------------
template <bool RELU, bool OUTBF>
__global__ __launch_bounds__(256)
void gemm_bt(const bf16_t* __restrict__ A, const bf16_t* __restrict__ B,
             const float* __restrict__ bias, void* __restrict__ Cv,
             int M, int N, int K)
{
  __shared__ bf16_t As[128 * 32];
  __shared__ bf16_t Bs[128 * 32];
  const int tid = threadIdx.x;
  const int lane = tid & 63, wave = tid >> 6;
  const int wr = (wave >> 1) * 64, wc = (wave & 1) * 64;
  const int lr = lane & 15, lk = (lane >> 4) * 8;
  const int m0 = blockIdx.x * 128, n0 = blockIdx.y * 128;

  const bf16_t* Ab = A + (size_t)m0 * K;
  const bf16_t* Bb = B + (size_t)n0 * K;

  f32x4 acc[4][4] = {};

  const int r0 = tid >> 2;                 // chunk tid     -> row 0..63
  const int r1 = (tid + 256) >> 2;         // chunk tid+256 -> row 64..127
  const int c0 = (tid & 3) * 8;            // col offset in BK

  for (int kk = 0; kk < K; kk += 32) {
    gload_lds16(Ab + (size_t)r0 * K + kk + c0, As + tid * 8);
    gload_lds16(Bb + (size_t)r0 * K + kk + c0, Bs + tid * 8);
    gload_lds16(Ab + (size_t)r1 * K + kk + c0, As + (tid + 256) * 8);
    gload_lds16(Bb + (size_t)r1 * K + kk + c0, Bs + (tid + 256) * 8);
    __syncthreads();
    bf16x8 af[4], bfr[4];
#pragma unroll
    for (int i = 0; i < 4; i++) af[i]  = *(const bf16x8*)(As + (wr + i * 16 + lr) * 32 + lk);
#pragma unroll
    for (int j = 0; j < 4; j++) bfr[j] = *(const bf16x8*)(Bs + (wc + j * 16 + lr) * 32 + lk);
#pragma unroll
    for (int i = 0; i < 4; i++)
#pragma unroll
      for (int j = 0; j < 4; j++)
        acc[i][j] = __builtin_amdgcn_mfma_f32_16x16x32_bf16(af[i], bfr[j], acc[i][j], 0, 0, 0);
    __syncthreads();
  }

  const int rg = (lane >> 4) * 4;
#pragma unroll
  for (int j = 0; j < 4; j++) {
    const int col = n0 + wc + j * 16 + lr;
    const float bv = bias ? bias[col] : 0.0f;
#pragma unroll
    for (int i = 0; i < 4; i++) {
#pragma unroll
      for (int r = 0; r < 4; r++) {
        const int row = m0 + wr + i * 16 + rg + r;
        float v = acc[i][j][r] + bv;
        if (RELU) v = fmaxf(v, 0.0f);
        if (OUTBF) ((bf16_t*)Cv)[(size_t)row * N + col] = (bf16_t)v;
        else       ((float*)Cv)[(size_t)row * N + col]  = v;
      }
    }
  }
}

// ------------------------------------------------------------------
// Flash attention: qkv (8192 x 1536 bf16: Q|K|V each h*64 cols),
// block = (b*8+h, qtile of 64 rows). 4 waves x 16 q-rows.
// ------------------------------------------------------------------
__global__ __launch_bounds__(256)
void k_attn(const bf16_t* __restrict__ qkv, bf16_t* __restrict__ out)
{
  const int bh = blockIdx.x;            // b*8+h
  const int qt = blockIdx.y;            // 0..15
  const int b = bh >> 3, h = bh & 7;
  const int tid = threadIdx.x, lane = tid & 63, wave = tid >> 6;
  const int lr = lane & 15, lg = lane >> 4;

  __shared__ bf16_t Vt[64][72];         // V^T (d x key), padded
  __shared__ bf16_t Pl[64][72];         // P (q x key), padded

  const size_t RS = 1536;
  const bf16_t* Qb = qkv + ((size_t)(b * 1024 + qt * 64)) * RS + h * 64;
  const bf16_t* Kb = qkv + ((size_t)(b * 1024)) * RS + 512 + h * 64;
  const bf16_t* Vb = Kb + 512;

  bf16x8 qf[2];
#pragma unroll
  for (int ks = 0; ks < 2; ks++)
    qf[ks] = *(const bf16x8*)(Qb + (size_t)(wave * 16 + lr) * RS + lg * 8 + ks * 32);

  f32x4 o[4] = {};
  float m[4], lsum[4];
#pragma unroll
  for (int r = 0; r < 4; r++) { m[r] = -1e30f; lsum[r] = 0.0f; }

  for (int kv = 0; kv < 16; kv++) {
    __syncthreads();                     // protect Vt from previous-iter readers
    for (int c = tid; c < 512; c += 256) {
      const int key = c >> 3, d0 = (c & 7) * 8;
      bf16x8 v = *(const bf16x8*)(Vb + (size_t)(kv * 64 + key) * RS + d0);
#pragma unroll
      for (int u = 0; u < 8; u++) Vt[d0 + u][key] = v[u];
    }
    __syncthreads();

    f32x4 sfr[4];
#pragma unroll
    for (int j = 0; j < 4; j++) {
      f32x4 z = {};
#pragma unroll
      for (int ks = 0; ks < 2; ks++) {
        bf16x8 kf = *(const bf16x8*)(Kb + (size_t)(kv * 64 + j * 16 + lr) * RS + lg * 8 + ks * 32);
        z = __builtin_amdgcn_mfma_f32_16x16x32_bf16(qf[ks], kf, z, 0, 0, 0);
      }
#pragma unroll
      for (int r = 0; r < 4; r++) z[r] *= 0.125f;  // 1/sqrt(64)
      sfr[j] = z;
    }

    float alpha[4];
#pragma unroll
    for (int r = 0; r < 4; r++) {
      float mx = fmaxf(fmaxf(sfr[0][r], sfr[1][r]), fmaxf(sfr[2][r], sfr[3][r]));
#pragma unroll
      for (int mk = 1; mk < 16; mk <<= 1) mx = fmaxf(mx, __shfl_xor(mx, mk, 64));
      const float mn = fmaxf(m[r], mx);
      alpha[r] = __expf(m[r] - mn);
      m[r] = mn;
    }
    float rs[4] = {0.0f, 0.0f, 0.0f, 0.0f};
#pragma unroll
    for (int j = 0; j < 4; j++)
#pragma unroll
      for (int r = 0; r < 4; r++) {
        const float p = __expf(sfr[j][r] - m[r]);
        sfr[j][r] = p;
        rs[r] += p;
      }
#pragma unroll
    for (int r = 0; r < 4; r++) {
#pragma unroll
      for (int mk = 1; mk < 16; mk <<= 1) rs[r] += __shfl_xor(rs[r], mk, 64);
      lsum[r] = lsum[r] * alpha[r] + rs[r];
    }
    // P -> LDS (per-wave private rows, no barrier needed)
#pragma unroll
    for (int j = 0; j < 4; j++)
#pragma unroll
      for (int r = 0; r < 4; r++)
        Pl[wave * 16 + lg * 4 + r][j * 16 + lr] = (bf16_t)sfr[j][r];
#pragma unroll
    for (int j = 0; j < 4; j++)
#pragma unroll
      for (int r = 0; r < 4; r++)
        o[j][r] *= alpha[r];
    // O += P * V   (NT with Vt)
#pragma unroll
    for (int ks = 0; ks < 2; ks++) {
      bf16x8 pa = *(const bf16x8*)(&Pl[wave * 16 + lr][lg * 8 + ks * 32]);
#pragma unroll
      for (int j = 0; j < 4; j++) {
        bf16x8 vb = *(const bf16x8*)(&Vt[j * 16 + lr][lg * 8 + ks * 32]);
        o[j] = __builtin_amdgcn_mfma_f32_16x16x32_bf16(pa, vb, o[j], 0, 0, 0);
      }
    }
  }

  const size_t orow = (size_t)(b * 1024 + qt * 64 + wave * 16 + lg * 4);
#pragma unroll
  for (int j = 0; j < 4; j++)
#pragma unroll
    for (int r = 0; r < 4; r++)
      out[(orow + r) * 512 + h * 64 + j * 16 + lr] = (bf16_t)(o[j][r] / lsum[r]);
}

// ------------------------------------------------------------------
// s += pos + ts[step]; p = sigmoid(s . p_w + p_b); ACT halting update.
// Also emits bf16 copy of s for the QKV GEMM.
// ------------------------------------------------------------------
__global__ __launch_bounds__(256)
void k_poshalt(float* __restrict__ s, bf16_t* __restrict__ xbf,
               const float* __restrict__ pos, const float* __restrict__ ts, int step,
               const float* __restrict__ pw, const float* __restrict__ pb,
               float* __restrict__ hp, float* __restrict__ rem, float* __restrict__ uw)
{
  const int row = blockIdx.x;
  const int l = row & 1023;
  const int t = threadIdx.x;
  const size_t base = (size_t)row * 512;
  float v0 = s[base + t]       + pos[l * 512 + t]       + ts[step * 512 + t];
  float v1 = s[base + 256 + t] + pos[l * 512 + 256 + t] + ts[step * 512 + 256 + t];
  s[base + t] = v0; s[base + 256 + t] = v1;
  xbf[base + t] = (bf16_t)v0; xbf[base + 256 + t] = (bf16_t)v1;

  float d = v0 * pw[t] + v1 * pw[256 + t];
#pragma unroll
  for (int mk = 1; mk < 64; mk <<= 1) d += __shfl_xor(d, mk, 64);
  __shared__ float part[4];
  if ((t & 63) == 0) part[t >> 6] = d;
  __syncthreads();
  if (t == 0) {
    const float z = part[0] + part[1] + part[2] + part[3] + pb[0];
    const float p = 1.0f / (1.0f + expf(-z));
    float h  = (step == 0) ? 0.0f : hp[row];
    float rm = (step == 0) ? 0.0f : rem[row];
    const float still0 = (h < 1.0f) ? 1.0f : 0.0f;
    const float cond = h + p * still0;
    const float nh = (cond > 0.9f) ? still0 : 0.0f;
    const float st = (cond <= 0.9f) ? still0 : 0.0f;
    h += p * st;
    rm += nh * (1.0f - h);
    h += nh * rm;
    hp[row] = h; rem[row] = rm;
    uw[row] = p * st + nh * rm;
  }
}

// ------------------------------------------------------------------
// y = LayerNorm(xa + xb) * g + be.
// UPDATE=false: write y (fp32) + y (bf16)      [post-attn LN]
// UPDATE=true : write y to s; prev = y*uw + prev*(1-uw)  [post-FFN LN]
// ------------------------------------------------------------------
template <bool UPDATE>
__global__ __launch_bounds__(256)
void k_addln(const float* __restrict__ xa, const float* __restrict__ xb,
             const float* __restrict__ g, const float* __restrict__ be,
             float* __restrict__ yout, bf16_t* __restrict__ ybf,
             const float* __restrict__ uw, float* __restrict__ prev, int step)
{
  const int row = blockIdx.x, t = threadIdx.x;
  const size_t base = (size_t)row * 512;
  const float v0 = xa[base + t] + xb[base + t];
  const float v1 = xa[base + 256 + t] + xb[base + 256 + t];
  float s1 = v0 + v1, s2 = v0 * v0 + v1 * v1;
#pragma unroll
  for (int mk = 1; mk < 64; mk <<= 1) { s1 += __shfl_xor(s1, mk, 64); s2 += __shfl_xor(s2, mk, 64); }
  __shared__ float p1[4], p2[4];
  if ((t & 63) == 0) { p1[t >> 6] = s1; p2[t >> 6] = s2; }
  __syncthreads();
  s1 = p1[0] + p1[1] + p1[2] + p1[3];
  s2 = p2[0] + p2[1] + p2[2] + p2[3];
  const float mean = s1 * (1.0f / 512.0f);
  const float var  = s2 * (1.0f / 512.0f) - mean * mean;
  const float ri = rsqrtf(var + 1e-5f);
  const float y0 = (v0 - mean) * ri * g[t]       + be[t];
  const float y1 = (v1 - mean) * ri * g[256 + t] + be[256 + t];
  if (UPDATE) {
    yout[base + t] = y0; yout[base + 256 + t] = y1;       // new state s
    const float w = uw[row];
    const float pv0 = (step == 0) ? 0.0f : prev[base + t];
    const float pv1 = (step == 0) ? 0.0f : prev[base + 256 + t];
    prev[base + t]       = y0 * w + pv0 * (1.0f - w);
    prev[base + 256 + t] = y1 * w + pv1 * (1.0f - w);
  } else {
    yout[base + t] = y0; yout[base + 256 + t] = y1;       // x1 fp32
    ybf[base + t] = (bf16_t)y0; ybf[base + 256 + t] = (bf16_t)y1;
  }
}

// ------------------------------------------------------------------
// Positional / timing tables (matches numpy f32 formula).
// ------------------------------------------------------------------
__global__ void k_pos_ts(float* __restrict__ pos, float* __restrict__ ts,
                         const int* __restrict__ outer)
{
  const int idx = blockIdx.x * 256 + threadIdx.x;   // 0 .. 1024*512-1
  const int l = idx >> 9, i = idx & 511;
  const float dt = expf((float)(i & ~1) * (-9.210340371976184f / 512.0f));
  const float a = (float)l * dt;
  pos[idx] = (i & 1) ? cosf(a) : sinf(a);
  if (l < 6) {
    const int gidx = 6 * outer[0] + l;
    const float a2 = (float)gidx * dt;
    ts[l * 512 + i] = (i & 1) ? cosf(a2) : sinf(a2);
  }
}

__global__ void k_f2b(const float* __restrict__ in, bf16_t* __restrict__ out, int n)
{
  const int i = blockIdx.x * 256 + threadIdx.x;
  if (i < n) out[i] = (bf16_t)in[i];
}

__global__ void k_copy(const float* __restrict__ in, float* __restrict__ out, int n)
{
  const int i = blockIdx.x * 256 + threadIdx.x;
  if (i < n) out[i] = in[i];
}

// ------------------------------------------------------------------
extern "C" void kernel_launch(void* const* d_in, const int* in_sizes, int n_in,
                              void* d_out, int out_size, void* d_ws, size_t ws_size,
                              hipStream_t stream)
{
  const float* state = (const float*)d_in[0];
  const int*   outer = (const int*)d_in[1];
  const float* p_w   = (const float*)d_in[2];
  const float* p_b   = (const float*)d_in[3];
  const float* wq = (const float*)d_in[4];
  const float* bq = (const float*)d_in[5];
  const float* wk = (const float*)d_in[6];
  const float* bk = (const float*)d_in[7];
  const float* wv = (const float*)d_in[8];
  const float* bv = (const float*)d_in[9];
  const float* wo = (const float*)d_in[10];
  const float* bo = (const float*)d_in[11];
  const float* w1 = (const float*)d_in[12];
  const float* b1 = (const float*)d_in[13];
  const float* w2 = (const float*)d_in[14];
  const float* b2 = (const float*)d_in[15];
  const float* ln1g = (const float*)d_in[16];
  const float* ln1b = (const float*)d_in[17];
  const float* ln2g = (const float*)d_in[18];
  const float* ln2b = (const float*)d_in[19];
  float* prev = (float*)d_out;

  char* cur = (char*)d_ws;
  auto take = [&](size_t n) { char* p = cur; cur += (n + 255) & ~(size_t)255; return p; };
  float*  pos   = (float*) take((size_t)1024 * 512 * 4);
  float*  ts    = (float*) take(6 * 512 * 4);
  bf16_t* wqkvB = (bf16_t*)take((size_t)1536 * 512 * 2);
  bf16_t* woB   = (bf16_t*)take((size_t)512 * 512 * 2);
  bf16_t* w1B   = (bf16_t*)take((size_t)2048 * 512 * 2);
  bf16_t* w2B   = (bf16_t*)take((size_t)512 * 2048 * 2);
  float*  bqkv  = (float*) take(1536 * 4);
  float*  s     = (float*) take((size_t)8192 * 512 * 4);
  float*  x1    = (float*) take((size_t)8192 * 512 * 4);
  bf16_t* x1B   = (bf16_t*)take((size_t)8192 * 512 * 2);
  float*  tmp   = (float*) take((size_t)8192 * 512 * 4);
  bf16_t* attnO = (bf16_t*)take((size_t)8192 * 512 * 2);
  float*  hp    = (float*) take(8192 * 4);
  float*  rem   = (float*) take(8192 * 4);
  float*  uw    = (float*) take(8192 * 4);
  char*   region = take((size_t)8192 * 2048 * 2);           // 33.5 MB, time-shared
  bf16_t* xB  = (bf16_t*)region;                            // 8192x512  (dead after QKV gemm)
  bf16_t* qkv = (bf16_t*)(region + (size_t)8192 * 512 * 2); // 8192x1536 (dead after attn)
  bf16_t* hB  = (bf16_t*)region;                            // 8192x2048 (FFN intermediate)

  // ---- precompute ----
  k_pos_ts<<<dim3(2048), dim3(256), 0, stream>>>(pos, ts, outer);
  k_f2b<<<dim3(1024), dim3(256), 0, stream>>>(wq, wqkvB,               512 * 512);
  k_f2b<<<dim3(1024), dim3(256), 0, stream>>>(wk, wqkvB + 512 * 512,   512 * 512);
  k_f2b<<<dim3(1024), dim3(256), 0, stream>>>(wv, wqkvB + 1024 * 512,  512 * 512);
  k_f2b<<<dim3(1024), dim3(256), 0, stream>>>(wo, woB,                 512 * 512);
  k_f2b<<<dim3(4096), dim3(256), 0, stream>>>(w1, w1B,                 2048 * 512);
  k_f2b<<<dim3(4096), dim3(256), 0, stream>>>(w2, w2B,                 512 * 2048);
  k_copy<<<dim3(2), dim3(256), 0, stream>>>(bq, bqkv,        512);
  k_copy<<<dim3(2), dim3(256), 0, stream>>>(bk, bqkv + 512,  512);
  k_copy<<<dim3(2), dim3(256), 0, stream>>>(bv, bqkv + 1024, 512);
  k_copy<<<dim3(16384), dim3(256), 0, stream>>>(state, s, 8192 * 512);

  // ---- 6 hops ----
  for (int step = 0; step < 6; step++) {
    k_poshalt<<<dim3(8192), dim3(256), 0, stream>>>(s, xB, pos, ts, step, p_w, p_b, hp, rem, uw);
    gemm_bt<false, true ><<<dim3(64, 12), dim3(256), 0, stream>>>(xB, wqkvB, bqkv, (void*)qkv, 8192, 1536, 512);
    k_attn<<<dim3(64, 16), dim3(256), 0, stream>>>(qkv, attnO);
    gemm_bt<false, false><<<dim3(64, 4),  dim3(256), 0, stream>>>(attnO, woB, bo, (void*)tmp, 8192, 512, 512);
    k_addln<false><<<dim3(8192), dim3(256), 0, stream>>>(s, tmp, ln1g, ln1b, x1, x1B, nullptr, nullptr, step);
    gemm_bt<true,  true ><<<dim3(64, 16), dim3(256), 0, stream>>>(x1B, w1B, b1, (void*)hB, 8192, 2048, 512);
    gemm_bt<false, false><<<dim3(64, 4),  dim3(256), 0, stream>>>(hB, w2B, b2, (void*)tmp, 8192, 512, 2048);
    k_addln<true ><<<dim3(8192), dim3(256), 0, stream>>>(x1, tmp, ln2g, ln2b, s, nullptr, uw, prev, step);
  }
}